// Round 7
// baseline (15855.803 us; speedup 1.0000x reference)
//
#include <hip/hip_runtime.h>

// R7: kernel-boundary synchronization. The persistent grid barrier (R1-R6)
// cost ~26-42 us/step regardless of mechanism (agent fences / relaxed+1-fence
// / sc0sc1 bypass / fillers at 92% VALUBusy) -- so use the sync path the
// driver natively optimizes: 512 dependent graph nodes. gates_x precomputed
// in a parallel prepass (proven R6); each step kernel does h@Wh + gates +
// nonlinearity only. No flags, no fences, no fillers, plain cached loads.

typedef unsigned short u16;
typedef unsigned int u32;
typedef __attribute__((ext_vector_type(8))) short bf16x8;
typedef __attribute__((ext_vector_type(4))) float f32x4;

#define NBLK 64
#define SEQ 512
#define BATCH 64
#define HID 1024
#define KDIM 2048
#define NGATES 4096
#define GB_STRIDE 68
#define XS_STRIDE 1032                 // 1024 + 8 pad
#define SMEM_PP (64 * XS_STRIDE * 2)   // prepass LDS: 132096 B

__device__ __forceinline__ u16 f2bf(float f) {
  u32 u = __builtin_bit_cast(u32, f);
  u += 0x7FFFu + ((u >> 16) & 1u);   // RNE
  return (u16)(u >> 16);
}
__device__ __forceinline__ float bf2f(u32 v) {
  return __builtin_bit_cast(float, v << 16);
}

// ---------- prep: W [2048][4096] f32 -> Wt [4096][2048] bf16 (transposed) ----------
__global__ void prep_w(const float* __restrict__ W, u16* __restrict__ Wt) {
  __shared__ float tile[64][65];
  const int kb = blockIdx.x * 64;
  const int nb = blockIdx.y * 64;
  const int tx = threadIdx.x & 63;
  const int ty = threadIdx.x >> 6;
  for (int r = ty; r < 64; r += 4)
    tile[r][tx] = W[(size_t)(kb + r) * NGATES + nb + tx];
  __syncthreads();
  for (int r = ty; r < 64; r += 4)
    Wt[(size_t)(nb + r) * KDIM + kb + tx] = f2bf(tile[tx][r]);
}

// ---------- prep: x f32 -> bf16 ----------
__global__ void prep_x(const float* __restrict__ x, u16* __restrict__ xb) {
  const size_t n4 = (size_t)SEQ * BATCH * HID / 4;
  size_t i = (size_t)blockIdx.x * blockDim.x + threadIdx.x;
  const size_t stride = (size_t)gridDim.x * blockDim.x;
  for (; i < n4; i += stride) {
    const float4 v = *(const float4*)(x + i * 4);
    u32 lo = (u32)f2bf(v.x) | ((u32)f2bf(v.y) << 16);
    u32 hi = (u32)f2bf(v.z) | ((u32)f2bf(v.w) << 16);
    *(uint2*)(xb + i * 4) = make_uint2(lo, hi);
  }
}

// ---------- prep: broadcast h0 -> hbuf[0] (bf16), c0 -> cbuf (f32) ----------
__global__ void prep_hc(const float* __restrict__ h0, const float* __restrict__ c0,
                        u16* __restrict__ hbuf, float* __restrict__ cbuf) {
  const int i = blockIdx.x * blockDim.x + threadIdx.x;   // 0..65535
  const float hv = h0[i & (HID - 1)];
  hbuf[i] = f2bf(hv);
  cbuf[i] = c0[i & (HID - 1)];
}

// ---------- prepass: gxF[bid][t][g][c16][row64] bf16 = (x_t @ Wx) fragments ----------
// (unchanged from R6 -- proven correct)
__global__ __launch_bounds__(512) void prepass_gx(
    const u16* __restrict__ xb, const u16* __restrict__ Wt, u16* __restrict__ gxF)
{
  extern __shared__ u16 xs[];     // [64][XS_STRIDE]
  const int tid = threadIdx.x;
  const int lane = tid & 63;
  const int wv = tid >> 6;
  const int col16 = lane & 15;
  const int kg = lane >> 4;
  const int t0 = blockIdx.x * 2;

  for (int tp = 0; tp < 2; ++tp) {
    const int t = t0 + tp;
    if (tp) __syncthreads();
    const u16* xsrc = xb + (size_t)t * (BATCH * HID);
    #pragma unroll
    for (int it = 0; it < 16; ++it) {
      const int flat = it * 512 + tid;
      const int row = flat >> 7, k0 = (flat & 127) * 8;
      *(bf16x8*)(xs + row * XS_STRIDE + k0) = *(const bf16x8*)(xsrc + row * HID + k0);
    }
    __syncthreads();
    const int g = wv >> 1;
    for (int nt = 0; nt < 32; ++nt) {
      const int col = wv * 512 + nt * 16 + col16;
      const u16* bp = Wt + (size_t)col * KDIM + HID + kg * 8;
      f32x4 acc[4];
      #pragma unroll
      for (int mt = 0; mt < 4; ++mt) acc[mt] = (f32x4){0.f, 0.f, 0.f, 0.f};
      #pragma unroll 4
      for (int kt = 0; kt < 32; ++kt) {
        const bf16x8 bw = *(const bf16x8*)(bp + kt * 32);
        #pragma unroll
        for (int mt = 0; mt < 4; ++mt) {
          const bf16x8 av = *(const bf16x8*)(xs + (mt * 16 + col16) * XS_STRIDE
                                                + kt * 32 + kg * 8);
          acc[mt] = __builtin_amdgcn_mfma_f32_16x16x32_bf16(av, bw, acc[mt], 0, 0, 0);
        }
      }
      const int bid16 = (wv & 1) * 32 + nt;
      #pragma unroll
      for (int mt = 0; mt < 4; ++mt) {
        u16* dst = gxF + ((((size_t)bid16 * SEQ + t) * 4 + g) * 16 + col16) * 64
                       + mt * 16 + kg * 4;
        const u32 lo = (u32)f2bf(acc[mt][0]) | ((u32)f2bf(acc[mt][1]) << 16);
        const u32 hi = (u32)f2bf(acc[mt][2]) | ((u32)f2bf(acc[mt][3]) << 16);
        *(uint2*)dst = make_uint2(lo, hi);
      }
    }
  }
}

// ---------- one recurrence step: gates = h_t@Wh + gx_t + b; h,c update ----------
// 64 blocks x 512 thr (8 waves = 4 K-quarters x 2 gate-pairs). Block owns 16
// hidden cols (all 4 gates). Sync/coherence: kernel boundary (CP L2 WB+INV).
__global__ __launch_bounds__(512) void lstm_step(
    const int t,
    const float* __restrict__ bias,  // [4096]
    const u16* __restrict__ Wt,      // [4096][2048] bf16
    const u16* __restrict__ gxF,     // [64][512][4][16][64] bf16
    u16* __restrict__ hbuf,          // [2][64][1024] bf16
    float* __restrict__ cbuf,        // [64][1024] f32
    float* __restrict__ out)         // [2][64][1024] f32
{
  __shared__ float gb[64 * GB_STRIDE];
  const int tid = threadIdx.x;
  const int lane = tid & 63;
  const int wave = tid >> 6;
  const int nh = wave & 1;        // gate pair
  const int kq = wave >> 1;       // K quarter
  const int col16 = lane & 15;
  const int kg = lane >> 4;
  const int bid = blockIdx.x;

  // ---- early loads: c-state, gx fragment, bias (off critical MFMA path) ----
  const int r0 = tid >> 4;
  const int colg = bid * 16 + (tid & 15);
  const float cold0 = cbuf[(size_t)r0 * HID + colg];
  const float cold1 = cbuf[(size_t)(r0 + 32) * HID + colg];

  uint2 gxr[8];
  if (kq == 0) {
    const u16* sb = gxF + ((size_t)bid * SEQ + t) * 4096;
    #pragma unroll
    for (int mt = 0; mt < 4; ++mt)
      #pragma unroll
      for (int nt = 0; nt < 2; ++nt)
        gxr[mt * 2 + nt] = *(const uint2*)(sb + ((nh * 2 + nt) * 16 + col16) * 64
                                              + mt * 16 + kg * 4);
  }
  const float bv0 = bias[(nh * 2 + 0) * HID + bid * 16 + col16];
  const float bv1 = bias[(nh * 2 + 1) * HID + bid * 16 + col16];

  // ---- Wh fragments (re-read each launch; L2/MALL-resident) ----
  bf16x8 wh[8][2];
  #pragma unroll
  for (int kt = 0; kt < 8; ++kt)
    #pragma unroll
    for (int nt = 0; nt < 2; ++nt)
      wh[kt][nt] = *(const bf16x8*)(Wt + (size_t)((nh * 2 + nt) * HID + bid * 16 + col16) * KDIM
                                       + kq * 256 + kt * 32 + kg * 8);

  // ---- h_t @ Wh ----
  const size_t aoff = (size_t)col16 * HID + kq * 256 + kg * 8;
  const u16* hbase = hbuf + (size_t)(t & 1) * (BATCH * HID) + aoff;
  f32x4 acc[4][2];
  #pragma unroll
  for (int mt = 0; mt < 4; ++mt) {
    acc[mt][0] = (f32x4){0.f, 0.f, 0.f, 0.f};
    acc[mt][1] = (f32x4){0.f, 0.f, 0.f, 0.f};
  }
  #pragma unroll
  for (int mt = 0; mt < 4; ++mt) {
    bf16x8 a[8];
    #pragma unroll
    for (int kt = 0; kt < 8; ++kt)
      a[kt] = *(const bf16x8*)(hbase + (size_t)mt * 16 * HID + kt * 32);
    #pragma unroll
    for (int kt = 0; kt < 8; ++kt) {
      acc[mt][0] = __builtin_amdgcn_mfma_f32_16x16x32_bf16(a[kt], wh[kt][0], acc[mt][0], 0, 0, 0);
      acc[mt][1] = __builtin_amdgcn_mfma_f32_16x16x32_bf16(a[kt], wh[kt][1], acc[mt][1], 0, 0, 0);
    }
  }

  // ---- K-reduction in LDS; kq0 seeds with bias + gates_x ----
  if (kq == 0) {
    #pragma unroll
    for (int mt = 0; mt < 4; ++mt)
      #pragma unroll
      for (int nt = 0; nt < 2; ++nt) {
        const float bv = nt ? bv1 : bv0;
        const uint2 gv = gxr[mt * 2 + nt];
        const float gx0 = bf2f(gv.x & 0xffffu), gx1 = bf2f(gv.x >> 16);
        const float gx2 = bf2f(gv.y & 0xffffu), gx3 = bf2f(gv.y >> 16);
        float* gp = gb + (mt * 16 + kg * 4) * GB_STRIDE + (nh * 2 + nt) * 16 + col16;
        gp[0 * GB_STRIDE] = acc[mt][nt][0] + bv + gx0;
        gp[1 * GB_STRIDE] = acc[mt][nt][1] + bv + gx1;
        gp[2 * GB_STRIDE] = acc[mt][nt][2] + bv + gx2;
        gp[3 * GB_STRIDE] = acc[mt][nt][3] + bv + gx3;
      }
  }
  __syncthreads();
  if (kq != 0) {
    #pragma unroll
    for (int mt = 0; mt < 4; ++mt)
      #pragma unroll
      for (int nt = 0; nt < 2; ++nt)
        #pragma unroll
        for (int r = 0; r < 4; ++r)
          atomicAdd(&gb[(mt * 16 + kg * 4 + r) * GB_STRIDE + (nh * 2 + nt) * 16 + col16],
                    acc[mt][nt][r]);
  }
  __syncthreads();

  // ---- gates -> nonlinearity -> c,h update (2 cells/thread) ----
  u16* hw = hbuf + (size_t)((t + 1) & 1) * (BATCH * HID);
  const int cl = tid & 15;
  #pragma unroll
  for (int cc = 0; cc < 2; ++cc) {
    const int row = r0 + cc * 32;
    const float vf = gb[row * GB_STRIDE + cl];
    const float vi = gb[row * GB_STRIDE + 16 + cl];
    const float vg = gb[row * GB_STRIDE + 32 + cl];
    const float vo = gb[row * GB_STRIDE + 48 + cl];
    const float ft = 1.f / (1.f + __expf(-vf));
    const float it = 1.f / (1.f + __expf(-vi));
    const float eg = __expf(2.f * vg);
    const float gt = 1.f - 2.f / (eg + 1.f);     // tanh
    const float ot = 1.f / (1.f + __expf(-vo));
    const float cold = cc ? cold1 : cold0;
    const float cn = ft * cold + it * gt;
    const float ec = __expf(2.f * cn);
    const float th = 1.f - 2.f / (ec + 1.f);     // tanh
    const float hn = ot * th;
    hw[(size_t)row * HID + colg] = f2bf(hn);
    cbuf[(size_t)row * HID + colg] = cn;
    if (t == SEQ - 1) {
      out[(size_t)row * HID + colg] = hn;
      out[(size_t)BATCH * HID + (size_t)row * HID + colg] = cn;
    }
  }
}

extern "C" void kernel_launch(void* const* d_in, const int* in_sizes, int n_in,
                              void* d_out, int out_size, void* d_ws, size_t ws_size,
                              hipStream_t stream) {
  const float* x    = (const float*)d_in[0];  // [512][64][1024]
  const float* W    = (const float*)d_in[1];  // [2048][4096]
  const float* bias = (const float*)d_in[2];  // [4096]
  const float* h0   = (const float*)d_in[3];  // [1024]
  const float* c0   = (const float*)d_in[4];  // [1024]
  float* out = (float*)d_out;                 // [2][64][1024]

  char* w = (char*)d_ws;
  u16* Wt    = (u16*)w;                                    // 16 MB
  u16* xbq   = (u16*)(w + ((size_t)16 << 20));             // 64 MB
  u16* hbuf  = (u16*)(w + ((size_t)80 << 20));             // 256 KB
  float* cbuf = (float*)(w + ((size_t)80 << 20) + (256 << 10));  // 256 KB
  u16* gxF   = (u16*)(w + ((size_t)81 << 20));             // 256 MB
  const size_t need = ((size_t)81 << 20) + ((size_t)256 << 20);
  if (ws_size < need) return;  // fail visibly rather than corrupt

  (void)hipFuncSetAttribute((const void*)prepass_gx,
                            hipFuncAttributeMaxDynamicSharedMemorySize, SMEM_PP);

  hipLaunchKernelGGL(prep_w, dim3(32, 64), dim3(256), 0, stream, W, Wt);
  hipLaunchKernelGGL(prep_x, dim3(4096), dim3(256), 0, stream, x, xbq);
  hipLaunchKernelGGL(prep_hc, dim3(256), dim3(256), 0, stream, h0, c0, hbuf, cbuf);
  hipLaunchKernelGGL(prepass_gx, dim3(256), dim3(512), SMEM_PP, stream, xbq, Wt, gxF);
  for (int t = 0; t < SEQ; ++t)
    hipLaunchKernelGGL(lstm_step, dim3(NBLK), dim3(512), 0, stream,
                       t, bias, Wt, gxF, hbuf, cbuf, out);
}

// Round 8
// 13317.178 us; speedup vs baseline: 1.1906x; 1.1906x over previous
//
#include <hip/hip_runtime.h>

// R8: R6 structure (gx prepass + Wh-in-VGPR + sc0sc1 h exchange), two changes:
//  (1) barrier flags spread to ONE 256B MALL line each (was 64 flags in 4
//      lines: 64 blocks x 64 lanes uncached-polling 4 lines ~ 9 txn/ns ->
//      release stores queue behind the read flood; serial visibility ~64 x
//      0.4us = the invariant ~25us/step R2-R7 never explained).
//  (2) poll backoff s_sleep(8). Fillers deleted (DVFS theory dead in R6).

typedef unsigned short u16;
typedef unsigned int u32;
typedef __attribute__((ext_vector_type(8))) short bf16x8;
typedef __attribute__((ext_vector_type(4))) float f32x4;

#define NBLK 64
#define SEQ 512
#define BATCH 64
#define HID 1024
#define KDIM 2048
#define NGATES 4096
#define GB_STRIDE 68
#define XS_STRIDE 1032                 // 1024 + 8 pad
#define SMEM_PP (64 * XS_STRIDE * 2)   // prepass LDS: 132096 B
#define FLAG_STRIDE 64                 // u32s between flags = 256 B/line

__device__ __forceinline__ u16 f2bf(float f) {
  u32 u = __builtin_bit_cast(u32, f);
  u += 0x7FFFu + ((u >> 16) & 1u);   // RNE
  return (u16)(u >> 16);
}
__device__ __forceinline__ float bf2f(u32 v) {
  return __builtin_bit_cast(float, v << 16);
}

// ---- LLC-coherent primitives (sc0 sc1 = device-coherent, bypass L1/L2) ----
__device__ __forceinline__ void llc_store_u16(u16* p, u16 v) {
  asm volatile("global_store_short %0, %1, off sc0 sc1" :: "v"(p), "v"((u32)v) : "memory");
}
__device__ __forceinline__ void llc_store_u32(u32* p, u32 v) {
  asm volatile("global_store_dword %0, %1, off sc0 sc1" :: "v"(p), "v"(v) : "memory");
}
__device__ __forceinline__ u32 llc_load_u32(const u32* p) {
  u32 r;
  asm volatile("global_load_dword %0, %1, off sc0 sc1\n\ts_waitcnt vmcnt(0)"
               : "=v"(r) : "v"(p) : "memory");
  return r;
}
#define LLC_LOAD8(dst, ap)                                                   \
  asm volatile("global_load_dwordx4 %0, %8, off sc0 sc1\n\t"                 \
               "global_load_dwordx4 %1, %8, off offset:64 sc0 sc1\n\t"       \
               "global_load_dwordx4 %2, %8, off offset:128 sc0 sc1\n\t"      \
               "global_load_dwordx4 %3, %8, off offset:192 sc0 sc1\n\t"      \
               "global_load_dwordx4 %4, %8, off offset:256 sc0 sc1\n\t"      \
               "global_load_dwordx4 %5, %8, off offset:320 sc0 sc1\n\t"      \
               "global_load_dwordx4 %6, %8, off offset:384 sc0 sc1\n\t"      \
               "global_load_dwordx4 %7, %8, off offset:448 sc0 sc1"          \
               : "=&v"(dst[0]), "=&v"(dst[1]), "=&v"(dst[2]), "=&v"(dst[3]), \
                 "=&v"(dst[4]), "=&v"(dst[5]), "=&v"(dst[6]), "=&v"(dst[7])  \
               : "v"(ap))

// ---------- prep: W [2048][4096] f32 -> Wt [4096][2048] bf16 (transposed); zero flags ----------
__global__ void prep_w(const float* __restrict__ W, u16* __restrict__ Wt,
                       u32* __restrict__ bar) {
  __shared__ float tile[64][65];
  const int kb = blockIdx.x * 64;
  const int nb = blockIdx.y * 64;
  const int tx = threadIdx.x & 63;
  const int ty = threadIdx.x >> 6;
  for (int r = ty; r < 64; r += 4)
    tile[r][tx] = W[(size_t)(kb + r) * NGATES + nb + tx];
  __syncthreads();
  for (int r = ty; r < 64; r += 4)
    Wt[(size_t)(nb + r) * KDIM + kb + tx] = f2bf(tile[tx][r]);
  if (blockIdx.x == 0 && blockIdx.y == 0)
    for (int i = threadIdx.x; i < NBLK * FLAG_STRIDE; i += 256)
      bar[i] = 0;
}

// ---------- prep: x f32 -> bf16 ----------
__global__ void prep_x(const float* __restrict__ x, u16* __restrict__ xb) {
  const size_t n4 = (size_t)SEQ * BATCH * HID / 4;
  size_t i = (size_t)blockIdx.x * blockDim.x + threadIdx.x;
  const size_t stride = (size_t)gridDim.x * blockDim.x;
  for (; i < n4; i += stride) {
    const float4 v = *(const float4*)(x + i * 4);
    u32 lo = (u32)f2bf(v.x) | ((u32)f2bf(v.y) << 16);
    u32 hi = (u32)f2bf(v.z) | ((u32)f2bf(v.w) << 16);
    *(uint2*)(xb + i * 4) = make_uint2(lo, hi);
  }
}

// ---------- prepass: gxF[bid][t][g][c16][row64] bf16 = (x_t @ Wx) fragments ----------
__global__ __launch_bounds__(512) void prepass_gx(
    const u16* __restrict__ xb, const u16* __restrict__ Wt, u16* __restrict__ gxF)
{
  extern __shared__ u16 xs[];     // [64][XS_STRIDE]
  const int tid = threadIdx.x;
  const int lane = tid & 63;
  const int wv = tid >> 6;
  const int col16 = lane & 15;
  const int kg = lane >> 4;
  const int t0 = blockIdx.x * 2;

  for (int tp = 0; tp < 2; ++tp) {
    const int t = t0 + tp;
    if (tp) __syncthreads();
    const u16* xsrc = xb + (size_t)t * (BATCH * HID);
    #pragma unroll
    for (int it = 0; it < 16; ++it) {
      const int flat = it * 512 + tid;
      const int row = flat >> 7, k0 = (flat & 127) * 8;
      *(bf16x8*)(xs + row * XS_STRIDE + k0) = *(const bf16x8*)(xsrc + row * HID + k0);
    }
    __syncthreads();
    const int g = wv >> 1;
    for (int nt = 0; nt < 32; ++nt) {
      const int col = wv * 512 + nt * 16 + col16;
      const u16* bp = Wt + (size_t)col * KDIM + HID + kg * 8;
      f32x4 acc[4];
      #pragma unroll
      for (int mt = 0; mt < 4; ++mt) acc[mt] = (f32x4){0.f, 0.f, 0.f, 0.f};
      #pragma unroll 4
      for (int kt = 0; kt < 32; ++kt) {
        const bf16x8 bw = *(const bf16x8*)(bp + kt * 32);
        #pragma unroll
        for (int mt = 0; mt < 4; ++mt) {
          const bf16x8 av = *(const bf16x8*)(xs + (mt * 16 + col16) * XS_STRIDE
                                                + kt * 32 + kg * 8);
          acc[mt] = __builtin_amdgcn_mfma_f32_16x16x32_bf16(av, bw, acc[mt], 0, 0, 0);
        }
      }
      const int bid16 = (wv & 1) * 32 + nt;
      #pragma unroll
      for (int mt = 0; mt < 4; ++mt) {
        u16* dst = gxF + ((((size_t)bid16 * SEQ + t) * 4 + g) * 16 + col16) * 64
                       + mt * 16 + kg * 4;
        const u32 lo = (u32)f2bf(acc[mt][0]) | ((u32)f2bf(acc[mt][1]) << 16);
        const u32 hi = (u32)f2bf(acc[mt][2]) | ((u32)f2bf(acc[mt][3]) << 16);
        *(uint2*)dst = make_uint2(lo, hi);
      }
    }
  }
}

// ---------- sequential LSTM: h-recurrence only ----------
__global__ __launch_bounds__(512) void lstm_seq(
    const float* __restrict__ bias,  // [4096]
    const float* __restrict__ h0,    // [1024]
    const float* __restrict__ c0,    // [1024]
    const u16* __restrict__ Wt,      // [4096][2048] bf16
    const u16* __restrict__ gxF,     // [64][512][4][16][64] bf16
    u16* __restrict__ hbuf,          // [2][64][1024] bf16 (LLC traffic)
    float* __restrict__ out,         // [2][64][1024] f32
    u32* __restrict__ bar)           // flags, 256B apart
{
  __shared__ float gb[64 * GB_STRIDE];
  const int tid = threadIdx.x;
  const int bid = blockIdx.x;
  const int lane = tid & 63;
  const int wave = tid >> 6;
  const int nh = wave & 1;        // gate pair
  const int kq = wave >> 1;       // K quarter
  const int col16 = lane & 15;
  const int kg = lane >> 4;

  // ---- one-time: Wh (h-half of Wt) -> VGPRs ----
  bf16x8 wh[8][2];
  #pragma unroll
  for (int kt = 0; kt < 8; ++kt)
    #pragma unroll
    for (int nt = 0; nt < 2; ++nt) {
      const int g = nh * 2 + nt;
      wh[kt][nt] = *(const bf16x8*)(Wt + (size_t)(g * HID + bid * 16 + col16) * KDIM
                                       + kq * 256 + kt * 32 + kg * 8);
    }
  const float bv0 = bias[(nh * 2 + 0) * HID + bid * 16 + col16];
  const float bv1 = bias[(nh * 2 + 1) * HID + bid * 16 + col16];

  // ---- per-thread output cells (rows r0, r0+32; col colg); c in regs ----
  const int r0 = tid >> 4;
  const int colg = bid * 16 + (tid & 15);
  float cst0 = c0[colg], cst1 = cst0;
  {
    const u16 h0b = f2bf(h0[colg]);
    llc_store_u16(hbuf + (size_t)r0 * HID + colg, h0b);
    llc_store_u16(hbuf + (size_t)(r0 + 32) * HID + colg, h0b);
  }
  __syncthreads();
  if (tid == 0) llc_store_u32(bar + bid * FLAG_STRIDE, 1u);

  // ---- loop-carried gx prefetch (kq==0 waves; private, L2-cached) ----
  uint2 gxr[8];
  auto gxload = [&](int t) {
    if (kq == 0) {
      const u16* sb = gxF + ((size_t)bid * SEQ + t) * 4096;
      #pragma unroll
      for (int mt = 0; mt < 4; ++mt)
        #pragma unroll
        for (int nt = 0; nt < 2; ++nt)
          gxr[mt * 2 + nt] = *(const uint2*)(sb + ((nh * 2 + nt) * 16 + col16) * 64
                                                + mt * 16 + kg * 4);
    }
  };
  gxload(0);

  f32x4 acc[4][2];
  const size_t aoff = (size_t)col16 * HID + kq * 256 + kg * 8;

  for (int t = 0; t < SEQ; ++t) {
    const u32 gen = (u32)t + 1;
    // ---- wait for h_t: one flag line per block, backoff poll ----
    if (tid < NBLK) {
      for (;;) {
        const u32 fl = llc_load_u32(bar + tid * FLAG_STRIDE);
        if (fl >= gen) break;
        __builtin_amdgcn_s_sleep(8);
      }
    }
    __syncthreads();

    // ---- h_t @ Wh: pipelined LLC loads + MFMA (acc from zero) ----
    #pragma unroll
    for (int mt = 0; mt < 4; ++mt) {
      acc[mt][0] = (f32x4){0.f, 0.f, 0.f, 0.f};
      acc[mt][1] = (f32x4){0.f, 0.f, 0.f, 0.f};
    }
    const u16* hbase = hbuf + (size_t)(t & 1) * (BATCH * HID) + aoff;
    {
      bf16x8 ha[8], hb2[8];
      asm volatile("s_waitcnt vmcnt(0)" ::: "memory");
      LLC_LOAD8(ha, hbase);
      #pragma unroll
      for (int mt = 0; mt < 4; ++mt) {
        if (mt < 3) {
          const u16* hn = hbase + (size_t)(mt + 1) * 16 * HID;
          if (mt & 1) { LLC_LOAD8(ha, hn); } else { LLC_LOAD8(hb2, hn); }
          asm volatile("s_waitcnt vmcnt(8)" ::: "memory");
        } else {
          asm volatile("s_waitcnt vmcnt(0)" ::: "memory");
        }
        __builtin_amdgcn_sched_barrier(0);
        #pragma unroll
        for (int kt = 0; kt < 8; ++kt) {
          const bf16x8 av = (mt & 1) ? hb2[kt] : ha[kt];
          acc[mt][0] = __builtin_amdgcn_mfma_f32_16x16x32_bf16(av, wh[kt][0], acc[mt][0], 0, 0, 0);
          acc[mt][1] = __builtin_amdgcn_mfma_f32_16x16x32_bf16(av, wh[kt][1], acc[mt][1], 0, 0, 0);
        }
      }
    }

    // ---- K-reduction in LDS; kq0 seeds with bias + gates_x ----
    if (kq == 0) {
      #pragma unroll
      for (int mt = 0; mt < 4; ++mt)
        #pragma unroll
        for (int nt = 0; nt < 2; ++nt) {
          const float bv = nt ? bv1 : bv0;
          const uint2 gv = gxr[mt * 2 + nt];
          const float gx0 = bf2f(gv.x & 0xffffu), gx1 = bf2f(gv.x >> 16);
          const float gx2 = bf2f(gv.y & 0xffffu), gx3 = bf2f(gv.y >> 16);
          float* gp = gb + (mt * 16 + kg * 4) * GB_STRIDE + (nh * 2 + nt) * 16 + col16;
          gp[0 * GB_STRIDE] = acc[mt][nt][0] + bv + gx0;
          gp[1 * GB_STRIDE] = acc[mt][nt][1] + bv + gx1;
          gp[2 * GB_STRIDE] = acc[mt][nt][2] + bv + gx2;
          gp[3 * GB_STRIDE] = acc[mt][nt][3] + bv + gx3;
        }
    }
    __syncthreads();
    if (kq != 0) {
      #pragma unroll
      for (int mt = 0; mt < 4; ++mt)
        #pragma unroll
        for (int nt = 0; nt < 2; ++nt)
          #pragma unroll
          for (int r = 0; r < 4; ++r)
            atomicAdd(&gb[(mt * 16 + kg * 4 + r) * GB_STRIDE + (nh * 2 + nt) * 16 + col16],
                      acc[mt][nt][r]);
    }
    __syncthreads();

    // ---- gates -> nonlinearity -> c,h update (2 cells/thread) ----
    u16* hw = hbuf + (size_t)((t + 1) & 1) * (BATCH * HID);
    const int cl = tid & 15;
    #pragma unroll
    for (int cc = 0; cc < 2; ++cc) {
      const int row = r0 + cc * 32;
      const float vf = gb[row * GB_STRIDE + cl];
      const float vi = gb[row * GB_STRIDE + 16 + cl];
      const float vg = gb[row * GB_STRIDE + 32 + cl];
      const float vo = gb[row * GB_STRIDE + 48 + cl];
      const float ft = 1.f / (1.f + __expf(-vf));
      const float it = 1.f / (1.f + __expf(-vi));
      const float eg = __expf(2.f * vg);
      const float gt = 1.f - 2.f / (eg + 1.f);     // tanh
      const float ot = 1.f / (1.f + __expf(-vo));
      const float cold = cc ? cst1 : cst0;
      const float cn = ft * cold + it * gt;
      const float ec = __expf(2.f * cn);
      const float th = 1.f - 2.f / (ec + 1.f);     // tanh
      const float hn = ot * th;
      if (cc) cst1 = cn; else cst0 = cn;
      llc_store_u16(hw + (size_t)row * HID + colg, f2bf(hn));
      if (t == SEQ - 1) {
        out[(size_t)row * HID + colg] = hn;
        out[(size_t)BATCH * HID + (size_t)row * HID + colg] = cn;
      }
    }
    __syncthreads();   // all waves' write-through h stores acked at LLC

    if (t < SEQ - 1) {
      if (tid == 0) llc_store_u32(bar + bid * FLAG_STRIDE, gen + 1);  // release
      gxload(t + 1);   // off-path prefetch
    }
  }
}

extern "C" void kernel_launch(void* const* d_in, const int* in_sizes, int n_in,
                              void* d_out, int out_size, void* d_ws, size_t ws_size,
                              hipStream_t stream) {
  const float* x    = (const float*)d_in[0];  // [512][64][1024]
  const float* W    = (const float*)d_in[1];  // [2048][4096]
  const float* bias = (const float*)d_in[2];  // [4096]
  const float* h0   = (const float*)d_in[3];  // [1024]
  const float* c0   = (const float*)d_in[4];  // [1024]
  float* out = (float*)d_out;                 // [2][64][1024]

  char* w = (char*)d_ws;
  u16* Wt   = (u16*)w;                                   // 16 MB
  u16* xbq  = (u16*)(w + ((size_t)16 << 20));            // 64 MB
  u16* hbuf = (u16*)(w + ((size_t)80 << 20));            // 256 KB
  u32* bar  = (u32*)(w + ((size_t)80 << 20) + (512 << 10));  // 16 KB (spread flags)
  u16* gxF  = (u16*)(w + ((size_t)81 << 20));            // 256 MB
  const size_t need = ((size_t)81 << 20) + ((size_t)256 << 20);
  if (ws_size < need) return;

  (void)hipFuncSetAttribute((const void*)prepass_gx,
                            hipFuncAttributeMaxDynamicSharedMemorySize, SMEM_PP);

  hipLaunchKernelGGL(prep_w, dim3(32, 64), dim3(256), 0, stream, W, Wt, bar);
  hipLaunchKernelGGL(prep_x, dim3(4096), dim3(256), 0, stream, x, xbq);
  hipLaunchKernelGGL(prepass_gx, dim3(256), dim3(512), SMEM_PP, stream, xbq, Wt, gxF);
  hipLaunchKernelGGL(lstm_seq, dim3(NBLK), dim3(512), 0, stream,
                     bias, h0, c0, Wt, gxF, hbuf, out, bar);
}